// Round 11
// baseline (136.354 us; speedup 1.0000x reference)
//
#include <hip/hip_runtime.h>
#include <hip/hip_bf16.h>

typedef __attribute__((ext_vector_type(8))) short short8;
typedef __attribute__((ext_vector_type(4))) float f32x4;
typedef __attribute__((ext_vector_type(16))) float f32x16;

#define LDSTB 514   // bf16 elems per LDS B row (512 + 2 pad): bank stride 257 ≡ 1 (odd)
                    // -> frag-read start banks = (l&31) + 4*(l>>5): exactly 2 lanes/bank (free)
#define LDS_BYTES (128 * LDSTB * 2)   // 131584 B

static __device__ __forceinline__ unsigned short f2bf(float f) {
    union { __hip_bfloat16 h; unsigned short u; } cv;
    cv.h = __float2bfloat16(f);
    return cv.u;
}

// Build Wbig[m=o*8+k][kk=f*8+j] = sum_i C[i,j,k] * W[i,o,f], cast to bf16.
__global__ __launch_bounds__(256) void build_wbig(const float* __restrict__ W,
                                                  unsigned short* __restrict__ Wbig) {
    __shared__ float C[8][8][8];
    const int t = threadIdx.x;
    for (int i = t; i < 512; i += 256) ((float*)C)[i] = 0.0f;
    __syncthreads();
    if (t == 0) {
        C[0][0][0] = 1.0f;
        for (int i = 1; i < 8; ++i) { C[0][i][i] = 1.0f; C[i][0][i] = 1.0f; C[i][i][0] = -1.0f; }
        const int tr[7][3] = {{1,2,3},{1,4,5},{1,7,6},{2,4,6},{2,5,7},{3,4,7},{3,6,5}};
        for (int q = 0; q < 7; ++q) {
            const int a = tr[q][0], b = tr[q][1], c = tr[q][2];
            const int p[3][3] = {{a,b,c},{b,c,a},{c,a,b}};
            for (int u = 0; u < 3; ++u) {
                C[p[u][0]][p[u][1]][p[u][2]] = 1.0f;
                C[p[u][1]][p[u][0]][p[u][2]] = -1.0f;
            }
        }
    }
    __syncthreads();
    const int e = blockIdx.x * 256 + t;     // 0..262143
    const int m = e >> 9, kk = e & 511;
    const int o = m >> 3, k = m & 7, f = kk >> 3, j = kk & 7;
    float s = 0.0f;
#pragma unroll
    for (int i = 0; i < 8; ++i) s += C[i][j][k] * W[i * 4096 + o * 64 + f];
    Wbig[e] = f2bf(s);
}

// Out[65536][512] = X(fp32->bf16) * Wbig^T + bias.
// Barrier-free streaming GEMM, mfma_f32_32x32x16_bf16:
//  - Block (1024 thr, 16 waves) owns 128 output cols; that ENTIRE B panel
//    (128 x 512 bf16 = 128.5 KB) is staged to LDS once -> one __syncthreads ->
//    no barriers ever again; waves free-run.
//  - A never staged: 32x32x16 A-frag = 32 B contiguous fp32 per lane, loaded
//    global->reg and cvt'd in-register (16 rows... 32 rows x 64 B segments).
//  - Wave job = 32 rows x 128 cols, acc[4] x f32x16 = 64 AGPR; 2 jobs/wave.
//  - 256 blocks = 1/CU; XCD swizzle co-locates the 4 col-group blocks of each
//    1024-row stripe (2 MB X slice fits the XCD's 4 MB L2).
__global__ __launch_bounds__(1024, 4) void oct_gemm(const float* __restrict__ X,
                                                    const unsigned short* __restrict__ Wbig,
                                                    const float* __restrict__ Bias,
                                                    float* __restrict__ Out) {
    extern __shared__ unsigned short Bs[];   // [128][LDSTB]

    const int d   = blockIdx.x;              // 0..255
    const int xcd = d & 7;
    const int i   = d >> 3;                  // 0..31
    const int rowBlock = xcd * 8 + (i >> 2); // 0..63 -> rows [rowBlock*1024, +1024)
    const int cg  = i & 3;                   // col group -> cols [cg*128, +128)
    const int colBase = cg * 128;

    const int t    = threadIdx.x;            // 0..1023
    const int lane = t & 63;
    const int w    = t >> 6;                 // wave 0..15
    const int l31  = lane & 31;
    const int l5   = lane >> 5;              // 0..1

    // ---- stage the block's whole B panel to LDS (once) ----
    {
        const int r  = t >> 3;               // 0..127
        const int c0 = (t & 7) * 64;         // 0..448
#pragma unroll
        for (int j = 0; j < 8; ++j) {
            short8 v = *reinterpret_cast<const short8*>(
                Wbig + (size_t)(colBase + r) * 512 + c0 + j * 8);
            *reinterpret_cast<short8*>(&Bs[r * LDSTB + c0 + j * 8]) = v;
        }
    }
    __syncthreads();   // the ONLY barrier

    // B frag LDS element offsets per nf (hoisted): row = nf*32 + l31, k-off = l5*8
    int boff[4];
#pragma unroll
    for (int nf = 0; nf < 4; ++nf)
        boff[nf] = (nf * 32 + l31) * LDSTB + l5 * 8;

#pragma unroll
    for (int job = 0; job < 2; ++job) {
        const int row0 = rowBlock * 1024 + (w * 2 + job) * 32;
        const float* Ap = X + (size_t)(row0 + l31) * 512 + l5 * 8;

        // acc init = bias (D col = lane&31 for all 16 regs of a frag)
        f32x16 acc[4];
#pragma unroll
        for (int nf = 0; nf < 4; ++nf) {
            const float bv = Bias[colBase + nf * 32 + l31];
#pragma unroll
            for (int r = 0; r < 16; ++r) acc[nf][r] = bv;
        }

        // ---- free-running K loop: 32 steps of K=16, no barriers ----
#pragma unroll 8
        for (int ks = 0; ks < 32; ++ks) {
            const f32x4 a0 = *reinterpret_cast<const f32x4*>(Ap + ks * 16);
            const f32x4 a1 = *reinterpret_cast<const f32x4*>(Ap + ks * 16 + 4);
            short8 bfr[4];
#pragma unroll
            for (int nf = 0; nf < 4; ++nf)
                bfr[nf] = *reinterpret_cast<const short8*>(&Bs[boff[nf] + ks * 16]);
            short8 af;
            af[0] = (short)f2bf(a0[0]); af[1] = (short)f2bf(a0[1]);
            af[2] = (short)f2bf(a0[2]); af[3] = (short)f2bf(a0[3]);
            af[4] = (short)f2bf(a1[0]); af[5] = (short)f2bf(a1[1]);
            af[6] = (short)f2bf(a1[2]); af[7] = (short)f2bf(a1[3]);
#pragma unroll
            for (int nf = 0; nf < 4; ++nf)
                acc[nf] = __builtin_amdgcn_mfma_f32_32x32x16_bf16(af, bfr[nf], acc[nf], 0, 0, 0);
        }

        // ---- epilogue: D row = (reg&3) + 8*(reg>>2) + 4*(l>>5), col = lane&31 ----
#pragma unroll
        for (int nf = 0; nf < 4; ++nf) {
            const int col = colBase + nf * 32 + l31;
#pragma unroll
            for (int r = 0; r < 16; ++r) {
                const int row = row0 + (r & 3) + 8 * (r >> 2) + 4 * l5;
                Out[(size_t)row * 512 + col] = acc[nf][r];
            }
        }
    }
}

extern "C" void kernel_launch(void* const* d_in, const int* in_sizes, int n_in,
                              void* d_out, int out_size, void* d_ws, size_t ws_size,
                              hipStream_t stream) {
    const float* x = (const float*)d_in[0];   // [65536][512]
    const float* W = (const float*)d_in[1];   // [8][64][64]
    const float* b = (const float*)d_in[2];   // [512]
    float* out = (float*)d_out;               // [65536][512]
    unsigned short* Wbig = (unsigned short*)d_ws;  // 512*512 bf16 = 512 KB

    static bool attr_done = false;
    if (!attr_done) {
        hipFuncSetAttribute((const void*)oct_gemm,
                            hipFuncAttributeMaxDynamicSharedMemorySize,
                            LDS_BYTES);
        attr_done = true;
    }

    build_wbig<<<1024, 256, 0, stream>>>(W, Wbig);
    oct_gemm<<<256, 1024, LDS_BYTES, stream>>>(x, Wbig, b, out);
}

// Round 12
// 64.996 us; speedup vs baseline: 2.0979x; 2.0979x over previous
//
#include <hip/hip_runtime.h>
#include <hip/hip_bf16.h>

typedef __attribute__((ext_vector_type(8))) short short8;
typedef __attribute__((ext_vector_type(4))) float f32x4;
typedef __attribute__((address_space(1))) const unsigned int as1_u32;
typedef __attribute__((address_space(3))) unsigned int as3_u32;

#define BM 256
#define BN 256
#define BK 64
#define LDSTA 72              // A LDS row: 64 + 8 pad (conflict-minimal, verified R1-R10)
#define NKT 8                 // 512 / BK
#define A_ELE (256 * LDSTA)   // 18432 bf16
#define B_ELE (256 * 64)      // 16384 bf16 (linear, swizzle baked into WbigS)
#define LDS_BYTES ((2 * A_ELE + 2 * B_ELE) * 2)   // 139264 B

static __device__ __forceinline__ unsigned short f2bf(float f) {
    union { __hip_bfloat16 h; unsigned short u; } cv;
    cv.h = __float2bfloat16(f);
    return cv.u;
}

__device__ __forceinline__ void gload16(const unsigned short* g, unsigned short* l) {
    __builtin_amdgcn_global_load_lds((as1_u32*)g, (as3_u32*)l, 16, 0, 0);
}

// Build WbigS: the octonion-folded weight, bf16, stored PRE-SWIZZLED as the
// exact DMA stream each GEMM block loads with global_load_lds.
// Logical Wbig[m][kk] = sum_i C[i,j,k] * W[i,o,f]  (m=o*8+k, kk=f*8+j).
// Stream layout: tile (ntile=m>>8, kt=kk>>6); within tile, granule (row=m&255,
// g_st = (c>>3) ^ (row&7)) holds logical k-granule c>>3 (c=kk&63), elem c&7:
//   WbigS[(((ntile*8+kt)*256 + row)*8 + g_st)*8 + (c&7)] = value.
__global__ __launch_bounds__(256) void build_wbig(const float* __restrict__ W,
                                                  unsigned short* __restrict__ WbigS) {
    __shared__ float C[8][8][8];
    const int t = threadIdx.x;
    for (int i = t; i < 512; i += 256) ((float*)C)[i] = 0.0f;
    __syncthreads();
    if (t == 0) {
        C[0][0][0] = 1.0f;
        for (int i = 1; i < 8; ++i) { C[0][i][i] = 1.0f; C[i][0][i] = 1.0f; C[i][i][0] = -1.0f; }
        const int tr[7][3] = {{1,2,3},{1,4,5},{1,7,6},{2,4,6},{2,5,7},{3,4,7},{3,6,5}};
        for (int q = 0; q < 7; ++q) {
            const int a = tr[q][0], b = tr[q][1], c = tr[q][2];
            const int p[3][3] = {{a,b,c},{b,c,a},{c,a,b}};
            for (int u = 0; u < 3; ++u) {
                C[p[u][0]][p[u][1]][p[u][2]] = 1.0f;
                C[p[u][1]][p[u][0]][p[u][2]] = -1.0f;
            }
        }
    }
    __syncthreads();
    const int e = blockIdx.x * 256 + t;     // 0..262143
    const int m = e >> 9, kk = e & 511;
    const int o = m >> 3, k = m & 7, f = kk >> 3, j = kk & 7;
    float s = 0.0f;
#pragma unroll
    for (int i = 0; i < 8; ++i) s += C[i][j][k] * W[i * 4096 + o * 64 + f];

    const int ntile = m >> 8, row = m & 255;
    const int kt = kk >> 6, c = kk & 63;
    const int g_st = (c >> 3) ^ (row & 7);
    WbigS[((((size_t)(ntile * 8 + kt) * 256 + row) * 8 + g_st) * 8) + (c & 7)] = f2bf(s);
}

// Out[65536][512] = X(fp32->bf16) * Wbig^T + bias.
// 256x256 tile, 8 waves. B: global_load_lds from pre-swizzled stream (0 regs,
// 0 VALU); A: depth-2 register prefetch + cvt + padded ds_write.
// In-order vmcnt discipline per iter:
//   GLOAD_B(t+1)[4] ; ISSUE_A(t+2)[8] ; MFMA(t) ; WRITE_A(t+1) [vmcnt(12):
//   retires A(t+1)] ; vmcnt(8) [retires B(t+1), leaves A(t+2) in flight] ;
//   lgkmcnt(0) ; raw s_barrier.  Global queue never drained mid-loop.
__global__ __launch_bounds__(512, 2) void oct_gemm(const float* __restrict__ X,
                                                   const unsigned short* __restrict__ WbigS,
                                                   const float* __restrict__ Bias,
                                                   float* __restrict__ Out) {
    extern __shared__ unsigned short smem[];
    unsigned short* As[2] = { smem,             smem + A_ELE };
    unsigned short* Bs[2] = { smem + 2 * A_ELE, smem + 2 * A_ELE + B_ELE };

    // XCD swizzle: both col-tiles of a row-tile on the same XCD.
    const int bid   = blockIdx.x;        // 0..511
    const int xcd   = bid & 7;
    const int ix    = bid >> 3;          // 0..63
    const int mtile = xcd * 32 + (ix >> 1);
    const int ntile = ix & 1;
    const int rowBase = mtile * BM;
    const int colBase = ntile * BN;

    const int t    = threadIdx.x;        // 0..511
    const int lane = t & 63;
    const int w    = t >> 6;             // 0..7
    const int wr   = w >> 2;             // 0..1  (128-row half)
    const int wc   = w & 3;              // 0..3  (64-col quarter)
    const int l15  = lane & 15;
    const int l4   = lane >> 4;          // 0..3

    const int srow = t >> 3;             // 0..63
    const int scol = (t & 7) * 8;        // 0..56
    const float* Xrow = X + (size_t)(rowBase + srow) * 512 + scol;

    f32x4 va0[8], va1[8];                // 2 in-flight A tiles (64 VGPR)

#define ISSUE_A(VA, KT) do { _Pragma("unroll") \
    for (int l = 0; l < 4; ++l) { \
        const float* src = Xrow + (size_t)(l * 64) * 512 + (KT) * BK; \
        VA[2*l]   = *reinterpret_cast<const f32x4*>(src); \
        VA[2*l+1] = *reinterpret_cast<const f32x4*>(src + 4); \
    } } while (0)

#define WRITE_A(VA, BUF) do { _Pragma("unroll") \
    for (int l = 0; l < 4; ++l) { \
        short8 p; \
        p[0]=(short)f2bf(VA[2*l][0]);   p[1]=(short)f2bf(VA[2*l][1]); \
        p[2]=(short)f2bf(VA[2*l][2]);   p[3]=(short)f2bf(VA[2*l][3]); \
        p[4]=(short)f2bf(VA[2*l+1][0]); p[5]=(short)f2bf(VA[2*l+1][1]); \
        p[6]=(short)f2bf(VA[2*l+1][2]); p[7]=(short)f2bf(VA[2*l+1][3]); \
        *reinterpret_cast<short8*>(&As[BUF][(l*64 + srow) * LDSTA + scol]) = p; \
    } } while (0)

    // 4 gload_lds per B tile: wave w, slice j -> 1 KB contiguous stream chunk.
#define GLOAD_B(BUF, KT) do { _Pragma("unroll") \
    for (int j = 0; j < 4; ++j) \
        gload16(WbigS + ((size_t)(ntile * 8 + (KT)) << 14) + (((w * 4 + j) * 64 + lane) << 3), \
                Bs[BUF] + ((w * 4 + j) << 9)); \
    } while (0)

    // Bias folded into accumulator init (D col = lane&15 for all 4 regs).
    f32x4 acc[8][4];
#pragma unroll
    for (int ni = 0; ni < 4; ++ni) {
        const float bv = Bias[colBase + wc * 64 + ni * 16 + l15];
#pragma unroll
        for (int mi = 0; mi < 8; ++mi) acc[mi][ni] = (f32x4){bv, bv, bv, bv};
    }

    // Prologue. Queue (oldest->newest): A0[8], B0[4], A1[8].
    ISSUE_A(va0, 0);
    GLOAD_B(0, 0);
    ISSUE_A(va1, 1);
    WRITE_A(va0, 0);                                   // compiler: vmcnt(12) -> A0 done
    asm volatile("s_waitcnt vmcnt(8) lgkmcnt(0)" ::: "memory");  // B0 done; A1 in flight
    __builtin_amdgcn_s_barrier();

#pragma unroll
    for (int kt = 0; kt < NKT; ++kt) {
        // B(t+1) first (oldest), then A(t+2): in-order vmcnt retirement works out.
        if (kt + 1 < NKT) GLOAD_B((kt + 1) & 1, kt + 1);
        if (kt + 2 < NKT) { if ((kt & 1) == 0) ISSUE_A(va0, kt + 2); else ISSUE_A(va1, kt + 2); }
        __builtin_amdgcn_sched_barrier(0);

        // MFMA phase: LDS-only operands.
#pragma unroll
        for (int kk = 0; kk < 2; ++kk) {
            short8 b[4];
#pragma unroll
            for (int ni = 0; ni < 4; ++ni) {
                const int row = wc * 64 + ni * 16 + l15;
                const int gs  = ((kk * 4 + l4) ^ (l15 & 7)) * 8;   // un-swizzle
                b[ni] = *reinterpret_cast<const short8*>(&Bs[kt & 1][row * 64 + gs]);
            }
            __builtin_amdgcn_s_setprio(1);
#pragma unroll
            for (int mi = 0; mi < 8; ++mi) {
                const short8 a = *reinterpret_cast<const short8*>(
                    &As[kt & 1][(wr * 128 + mi * 16 + l15) * LDSTA + kk * 32 + l4 * 8]);
#pragma unroll
                for (int ni = 0; ni < 4; ++ni)
                    acc[mi][ni] = __builtin_amdgcn_mfma_f32_16x16x32_bf16(
                        a, b[ni], acc[mi][ni], 0, 0, 0);
            }
            __builtin_amdgcn_s_setprio(0);
        }
        __builtin_amdgcn_sched_barrier(0);

        // Stage A(t+1): counted vmcnt retires exactly A(t+1)'s 8 loads.
        if (kt + 1 < NKT) { if ((kt & 1) == 0) WRITE_A(va1, 1); else WRITE_A(va0, 0); }

        if (kt + 2 < NKT)
            asm volatile("s_waitcnt vmcnt(8) lgkmcnt(0)" ::: "memory");  // B(t+1) done; A(t+2) flying
        else if (kt + 1 < NKT)
            asm volatile("s_waitcnt vmcnt(0) lgkmcnt(0)" ::: "memory");  // last prefetch drain
        else
            asm volatile("s_waitcnt lgkmcnt(0)" ::: "memory");
        __builtin_amdgcn_s_barrier();
    }

    // Epilogue: plain fp32 stores (clean 131 MB pattern, verified).
#pragma unroll
    for (int mi = 0; mi < 8; ++mi) {
        const int row0 = rowBase + wr * 128 + mi * 16 + l4 * 4;
#pragma unroll
        for (int ni = 0; ni < 4; ++ni) {
            const int col = colBase + wc * 64 + ni * 16 + l15;
#pragma unroll
            for (int r = 0; r < 4; ++r)
                Out[(size_t)(row0 + r) * 512 + col] = acc[mi][ni][r];
        }
    }
#undef ISSUE_A
#undef WRITE_A
#undef GLOAD_B
}

extern "C" void kernel_launch(void* const* d_in, const int* in_sizes, int n_in,
                              void* d_out, int out_size, void* d_ws, size_t ws_size,
                              hipStream_t stream) {
    const float* x = (const float*)d_in[0];   // [65536][512]
    const float* W = (const float*)d_in[1];   // [8][64][64]
    const float* b = (const float*)d_in[2];   // [512]
    float* out = (float*)d_out;               // [65536][512]
    unsigned short* WbigS = (unsigned short*)d_ws;  // 512 KB pre-swizzled stream

    static bool attr_done = false;
    if (!attr_done) {
        hipFuncSetAttribute((const void*)oct_gemm,
                            hipFuncAttributeMaxDynamicSharedMemorySize, LDS_BYTES);
        attr_done = true;
    }

    build_wbig<<<1024, 256, 0, stream>>>(W, WbigS);
    oct_gemm<<<512, 512, LDS_BYTES, stream>>>(x, WbigS, b, out);
}